// Round 6
// baseline (286.210 us; speedup 1.0000x reference)
//
#include <hip/hip_runtime.h>
#include <float.h>
#include <limits.h>

#define NB 64
#define NO 16
#define NP 5460
#define NCLS 81
#define NROWS (NB * NP)            // 349,440

// ws layout (bytes)
#define WS_ACCUM   0               // 3 doubles: [0]=conf [1]=loc [2]=cnt
#define WS_DONE    32              // unsigned completion counter
#define WS_WINNER  256
#define WS_CI      1398272
#define WS_OV      1660672

// ---------------------------------------------------------------------------
// Focal helpers — bitwise-identical between stream and fixup.
// ---------------------------------------------------------------------------
__device__ __forceinline__ float focal_neg(float s) {
    float e = __expf(-fabsf(s));
    float l1p = __logf(1.f + e);
    float q = __frcp_rn(1.f + e);
    float p = (s >= 0.f) ? q : e * q;
    return 0.75f * p * p * (fmaxf(s, 0.f) + l1p);
}
__device__ __forceinline__ float focal_pos(float s) {
    float e = __expf(-fabsf(s));
    float l1p = __logf(1.f + e);
    float q = __frcp_rn(1.f + e);
    float omp = (s >= 0.f) ? e * q : q;
    return 0.25f * omp * omp * (fmaxf(-s, 0.f) + l1p);
}

// ---------------------------------------------------------------------------
// K1: init (winner clear, accum/done zero) + analytic top-9 per (bo, level).
// Blocks 0..23 do topk (tid<6144); all 48 blocks share the winner clear.
// ---------------------------------------------------------------------------
__global__ __launch_bounds__(256) void topk_kernel(
    const float* __restrict__ boxes,   // [NB*NO, 4] xyxy
    int* __restrict__ ci_buf,          // [1024][64]
    float* __restrict__ ov_buf,        // [1024][64]
    int* __restrict__ winner,          // [NROWS]
    double* __restrict__ accum,
    unsigned* __restrict__ done)
{
    const int gtid = blockIdx.x * 256 + threadIdx.x;   // 0..12287

    // init accum + done flag
    if (gtid < 3) accum[gtid] = 0.0;
    if (gtid == 3) *done = 0u;

    // winner = -1 (349,440 ints = 87,360 int4)
    int4* w4 = reinterpret_cast<int4*>(winner);
    for (int i = gtid; i < NROWS / 4; i += 48 * 256)
        w4[i] = make_int4(-1, -1, -1, -1);

    if (gtid >= 6144) return;
    const int l  = gtid >> 10;
    const int bo = gtid & 1023;

    const int fms[6]   = {64, 32, 16, 8, 4, 2};
    const int lg2s[6]  = {6, 5, 4, 3, 2, 1};
    const int s0s[6]   = {0, 4096, 5120, 5376, 5440, 5456};
    const int basec[6] = {0, 9, 18, 27, 36, 45};
    const int fm = fms[l];
    const int lg2 = lg2s[l];
    const float fmf = (float)fm;

    const float4 bb = reinterpret_cast<const float4*>(boxes)[bo];
    const float bx0 = bb.x, by0 = bb.y, bx1 = bb.z, by1 = bb.w;
    const float bcx = (bx0 + bx1) * 0.5f;
    const float bcy = (by0 + by1) * 0.5f;
    const float barea = (bx1 - bx0) * (by1 - by0);

    int wx0 = 0, wy0 = 0, wnx = fm, wny = fm;
    if (fm >= 5) {
        int jx = (int)floorf(bcx * fmf);
        int jy = (int)floorf(bcy * fmf);
        jx = jx < 0 ? 0 : (jx > fm - 1 ? fm - 1 : jx);
        jy = jy < 0 ? 0 : (jy > fm - 1 ? fm - 1 : jy);
        wx0 = jx - 2; wx0 = wx0 < 0 ? 0 : (wx0 > fm - 5 ? fm - 5 : wx0);
        wy0 = jy - 2; wy0 = wy0 < 0 ? 0 : (wy0 > fm - 5 ? fm - 5 : wy0);
        wnx = 5; wny = 5;
    }

    float bv[9]; int bix[9];
    #pragma unroll
    for (int j = 0; j < 9; ++j) { bv[j] = FLT_MAX; bix[j] = INT_MAX; }

    for (int yy = 0; yy < wny; ++yy) {
        const int iy = wy0 + yy;
        const float py = ((float)iy + 0.5f) / fmf;
        const float dy = bcy - py;
        const float dy2 = dy * dy;
        for (int xx = 0; xx < wnx; ++xx) {
            const int ix = wx0 + xx;
            const float px = ((float)ix + 0.5f) / fmf;
            const float dx = bcx - px;
            const float d = dx * dx + dy2;
            const int gi = (iy << lg2) + ix;
            #pragma unroll
            for (int j = 8; j >= 0; --j) {
                bool ltp = (j > 0) ? (d < bv[j - 1]) : false;
                bool ltj = (d < bv[j]);
                float sv = ltp ? bv[j - 1] : (ltj ? d : bv[j]);
                int   si = ltp ? bix[j - 1] : (ltj ? gi : bix[j]);
                bv[j] = sv; bix[j] = si;
            }
        }
    }

    const int n = fm * fm;
    const int k = n < 9 ? n : 9;
    const float hw = 0.75f / fmf;
    const int obase = bo * 64 + basec[l];
    const int s0 = s0s[l];

    for (int j = 0; j < k; ++j) {
        const int li = bix[j];
        const int iy = li >> lg2, ix = li & (fm - 1);
        const float pcx = ((float)ix + 0.5f) / fmf;
        const float pcy = ((float)iy + 0.5f) / fmf;
        const float px0 = pcx - hw, py0 = pcy - hw;
        const float px1 = pcx + hw, py1 = pcy + hw;
        const float iw = fmaxf(fminf(bx1, px1) - fmaxf(bx0, px0), 0.f);
        const float ih = fmaxf(fminf(by1, py1) - fmaxf(by0, py0), 0.f);
        const float inter = iw * ih;
        const float parea = (px1 - px0) * (py1 - py0);
        const float ovv = inter / (barea + parea - inter + 1e-10f);
        ci_buf[obase + j] = s0 + li;
        ov_buf[obase + j] = ovv;
    }
}

// ---------------------------------------------------------------------------
// K2: threshold + positives + DIoU. One wave per (b,o). (Unchanged, passed.)
// ---------------------------------------------------------------------------
__global__ __launch_bounds__(256) void assign2_kernel(
    const float* __restrict__ locs,
    const float* __restrict__ boxes,
    const float* __restrict__ priors,
    const int* __restrict__ ci_buf,
    const float* __restrict__ ov_buf,
    int* __restrict__ winner,
    double* __restrict__ accum)
{
    const int w = threadIdx.x >> 6, lane = threadIdx.x & 63;
    const int bo = blockIdx.x * 4 + w;
    const int b = bo >> 4, o = bo & 15;

    const float4 bb = reinterpret_cast<const float4*>(boxes)[bo];
    const float bx0 = bb.x, by0 = bb.y, bx1 = bb.z, by1 = bb.w;
    const float bcx = (bx0 + bx1) * 0.5f, bcy = (by0 + by1) * 0.5f;
    const float barea = (bx1 - bx0) * (by1 - by0);

    int my_ci = 0; float ov = 0.f;
    if (lane < 49) {
        my_ci = ci_buf[bo * 64 + lane];
        ov    = ov_buf[bo * 64 + lane];
    }

    float sum = 0.f;
    for (int i = 0; i < 49; ++i) sum += __shfl(ov, i);
    const float mean = sum / 49.f;
    float ss = 0.f;
    for (int i = 0; i < 49; ++i) { float dd = __shfl(ov, i) - mean; ss += dd * dd; }
    const float thr = mean + sqrtf(ss / 48.f);

    float lloc = 0.f; int lcnt = 0;
    if (lane < 49) {
        const float4 pp = reinterpret_cast<const float4*>(priors)[my_ci];
        const bool inside = (bx0 <= pp.x) && (pp.x <= bx1) &&
                            (by0 <= pp.y) && (pp.y <= by1);
        if (inside && ov > thr) {
            atomicMax(&winner[b * NP + my_ci], o);
            const float4 g = reinterpret_cast<const float4*>(locs)[b * NP + my_ci];
            const float cx = g.x * pp.z * 0.1f + pp.x;
            const float cy = g.y * pp.w * 0.1f + pp.y;
            const float ww = __expf(g.z * 0.2f) * pp.z;
            const float hh = __expf(g.w * 0.2f) * pp.w;
            const float p0 = cx - ww * 0.5f, p1 = cy - hh * 0.5f;
            const float p2 = cx + ww * 0.5f, p3 = cy + hh * 0.5f;
            const float iw = fmaxf(fminf(p2, bx1) - fmaxf(p0, bx0), 0.f);
            const float ih = fmaxf(fminf(p3, by1) - fmaxf(p1, by0), 0.f);
            const float inter = iw * ih;
            const float ap = fmaxf(p2 - p0, 0.f) * fmaxf(p3 - p1, 0.f);
            const float iou = inter / (ap + barea - inter + 1e-7f);
            const float cpx = (p0 + p2) * 0.5f, cpy = (p1 + p3) * 0.5f;
            const float d2 = (cpx - bcx) * (cpx - bcx) + (cpy - bcy) * (cpy - bcy);
            const float ex0 = fminf(p0, bx0), ey0 = fminf(p1, by0);
            const float ex1 = fmaxf(p2, bx1), ey1 = fmaxf(p3, by1);
            const float dg = (ex1 - ex0) * (ex1 - ex0) + (ey1 - ey0) * (ey1 - ey0) + 1e-7f;
            lloc = 1.f - iou + d2 / dg;
            lcnt = 1;
        }
    }
    #pragma unroll
    for (int off = 32; off > 0; off >>= 1) {
        lloc += __shfl_xor(lloc, off);
        lcnt += __shfl_xor(lcnt, off);
    }
    if (lane == 0 && lcnt > 0) {
        atomicAdd(&accum[1], (double)lloc);
        atomicAdd(&accum[2], (double)lcnt);
    }
}

// ---------------------------------------------------------------------------
// K3: focal stream + row fixup + last-block finalize (completion counter).
// ---------------------------------------------------------------------------
#define K3_BLOCKS 2048
__global__ __launch_bounds__(256) void focal_fused_kernel(
    const float* __restrict__ scores,
    const int* __restrict__ winner,
    const int* __restrict__ labels,
    double* __restrict__ accum,
    unsigned* __restrict__ done,
    float* __restrict__ out)
{
    const unsigned tid = blockIdx.x * 256 + threadIdx.x;

    // --- streaming focal (all slots as negatives), 113 MB float4 ---
    const unsigned total4 = (unsigned)(NB * NP * NCLS / 4);
    const float4* s4 = reinterpret_cast<const float4*>(scores);
    float fsum = 0.f;
    for (unsigned i = tid; i < total4; i += K3_BLOCKS * 256) {
        float4 v = s4[i];
        fsum += focal_neg(v.x);
        fsum += focal_neg(v.y);
        fsum += focal_neg(v.z);
        fsum += focal_neg(v.w);
    }

    // --- per-row one-hot correction ---
    double d = (double)fsum;
    if (tid < NROWS) {
        const int w = winner[tid];
        const int L = (w >= 0) ? labels[(tid / NP) * NO + w] : 0;
        const float s = scores[tid * NCLS + L];
        d += (double)focal_pos(s) - (double)focal_neg(s);
    }

    // --- block reduce (double) + one atomic ---
    #pragma unroll
    for (int off = 32; off > 0; off >>= 1) d += __shfl_xor(d, off);
    __shared__ double redd[4];
    const int wid = threadIdx.x >> 6, lane = threadIdx.x & 63;
    if (lane == 0) redd[wid] = d;
    __syncthreads();
    if (threadIdx.x == 0) {
        atomicAdd(&accum[0], redd[0] + redd[1] + redd[2] + redd[3]);
        __threadfence();
        unsigned old = atomicAdd(done, 1u);
        if (old == (unsigned)gridDim.x - 1u) {
            // last block: read via device-scope RMWs (coherent), finalize
            double conf = atomicAdd(&accum[0], 0.0);
            double loc  = atomicAdd(&accum[1], 0.0);
            double cnt  = atomicAdd(&accum[2], 0.0);
            out[0] = (float)(conf / (double)NROWS +
                             loc / (cnt > 1.0 ? cnt : 1.0));
        }
    }
}

extern "C" void kernel_launch(void* const* d_in, const int* in_sizes, int n_in,
                              void* d_out, int out_size, void* d_ws, size_t ws_size,
                              hipStream_t stream) {
    const float* locs   = (const float*)d_in[0];
    const float* scores = (const float*)d_in[1];
    const float* boxes  = (const float*)d_in[2];
    const int*   labels = (const int*)d_in[3];
    const float* priors = (const float*)d_in[4];
    float* out = (float*)d_out;

    double*   accum  = (double*)((char*)d_ws + WS_ACCUM);
    unsigned* done   = (unsigned*)((char*)d_ws + WS_DONE);
    int*      winner = (int*)((char*)d_ws + WS_WINNER);
    int*      ci_buf = (int*)((char*)d_ws + WS_CI);
    float*    ov_buf = (float*)((char*)d_ws + WS_OV);

    topk_kernel<<<48, 256, 0, stream>>>(boxes, ci_buf, ov_buf, winner, accum, done);
    assign2_kernel<<<256, 256, 0, stream>>>(locs, boxes, priors, ci_buf, ov_buf,
                                            winner, accum);
    focal_fused_kernel<<<K3_BLOCKS, 256, 0, stream>>>(scores, winner, labels,
                                                      accum, done, out);
}

// Round 8
// 233.632 us; speedup vs baseline: 1.2250x; 1.2250x over previous
//
#include <hip/hip_runtime.h>
#include <float.h>
#include <limits.h>

#define NB 64
#define NO 16
#define NP 5460
#define NCLS 81
#define NROWS (NB * NP)            // 349,440

// ws layout (bytes)
#define WS_ACCUM   0               // 3 doubles: [0]=conf [1]=loc [2]=cnt
#define WS_WINNER  256
#define WS_CI      1398272
#define WS_OV      1660672

// ---------------------------------------------------------------------------
// Focal helpers — bitwise-identical between stream and fixup.
// ---------------------------------------------------------------------------
__device__ __forceinline__ float focal_neg(float s) {
    float e = __expf(-fabsf(s));
    float l1p = __logf(1.f + e);
    float q = __frcp_rn(1.f + e);
    float p = (s >= 0.f) ? q : e * q;
    return 0.75f * p * p * (fmaxf(s, 0.f) + l1p);
}
__device__ __forceinline__ float focal_pos(float s) {
    float e = __expf(-fabsf(s));
    float l1p = __logf(1.f + e);
    float q = __frcp_rn(1.f + e);
    float omp = (s >= 0.f) ? e * q : q;
    return 0.25f * omp * omp * (fmaxf(-s, 0.f) + l1p);
}

// ---------------------------------------------------------------------------
// K1: init (winner clear, accum zero) + analytic top-9 per (bo, level).
// ---------------------------------------------------------------------------
__global__ __launch_bounds__(256) void topk_kernel(
    const float* __restrict__ boxes,   // [NB*NO, 4] xyxy
    int* __restrict__ ci_buf,          // [1024][64]
    float* __restrict__ ov_buf,        // [1024][64]
    int* __restrict__ winner,          // [NROWS]
    double* __restrict__ accum)
{
    const int gtid = blockIdx.x * 256 + threadIdx.x;   // 0..12287

    if (gtid < 3) accum[gtid] = 0.0;

    // winner = -1 (349,440 ints = 87,360 int4)
    int4* w4 = reinterpret_cast<int4*>(winner);
    for (int i = gtid; i < NROWS / 4; i += 48 * 256)
        w4[i] = make_int4(-1, -1, -1, -1);

    if (gtid >= 6144) return;
    const int l  = gtid >> 10;
    const int bo = gtid & 1023;

    const int fms[6]   = {64, 32, 16, 8, 4, 2};
    const int lg2s[6]  = {6, 5, 4, 3, 2, 1};
    const int s0s[6]   = {0, 4096, 5120, 5376, 5440, 5456};
    const int basec[6] = {0, 9, 18, 27, 36, 45};
    const int fm = fms[l];
    const int lg2 = lg2s[l];
    const float fmf = (float)fm;

    const float4 bb = reinterpret_cast<const float4*>(boxes)[bo];
    const float bx0 = bb.x, by0 = bb.y, bx1 = bb.z, by1 = bb.w;
    const float bcx = (bx0 + bx1) * 0.5f;
    const float bcy = (by0 + by1) * 0.5f;
    const float barea = (bx1 - bx0) * (by1 - by0);

    int wx0 = 0, wy0 = 0, wnx = fm, wny = fm;
    if (fm >= 5) {
        int jx = (int)floorf(bcx * fmf);
        int jy = (int)floorf(bcy * fmf);
        jx = jx < 0 ? 0 : (jx > fm - 1 ? fm - 1 : jx);
        jy = jy < 0 ? 0 : (jy > fm - 1 ? fm - 1 : jy);
        wx0 = jx - 2; wx0 = wx0 < 0 ? 0 : (wx0 > fm - 5 ? fm - 5 : wx0);
        wy0 = jy - 2; wy0 = wy0 < 0 ? 0 : (wy0 > fm - 5 ? fm - 5 : wy0);
        wnx = 5; wny = 5;
    }

    float bv[9]; int bix[9];
    #pragma unroll
    for (int j = 0; j < 9; ++j) { bv[j] = FLT_MAX; bix[j] = INT_MAX; }

    for (int yy = 0; yy < wny; ++yy) {
        const int iy = wy0 + yy;
        const float py = ((float)iy + 0.5f) / fmf;
        const float dy = bcy - py;
        const float dy2 = dy * dy;
        for (int xx = 0; xx < wnx; ++xx) {
            const int ix = wx0 + xx;
            const float px = ((float)ix + 0.5f) / fmf;
            const float dx = bcx - px;
            const float d = dx * dx + dy2;
            const int gi = (iy << lg2) + ix;
            #pragma unroll
            for (int j = 8; j >= 0; --j) {
                bool ltp = (j > 0) ? (d < bv[j - 1]) : false;
                bool ltj = (d < bv[j]);
                float sv = ltp ? bv[j - 1] : (ltj ? d : bv[j]);
                int   si = ltp ? bix[j - 1] : (ltj ? gi : bix[j]);
                bv[j] = sv; bix[j] = si;
            }
        }
    }

    const int n = fm * fm;
    const int k = n < 9 ? n : 9;
    const float hw = 0.75f / fmf;
    const int obase = bo * 64 + basec[l];
    const int s0 = s0s[l];

    for (int j = 0; j < k; ++j) {
        const int li = bix[j];
        const int iy = li >> lg2, ix = li & (fm - 1);
        const float pcx = ((float)ix + 0.5f) / fmf;
        const float pcy = ((float)iy + 0.5f) / fmf;
        const float px0 = pcx - hw, py0 = pcy - hw;
        const float px1 = pcx + hw, py1 = pcy + hw;
        const float iw = fmaxf(fminf(bx1, px1) - fmaxf(bx0, px0), 0.f);
        const float ih = fmaxf(fminf(by1, py1) - fmaxf(by0, py0), 0.f);
        const float inter = iw * ih;
        const float parea = (px1 - px0) * (py1 - py0);
        const float ovv = inter / (barea + parea - inter + 1e-10f);
        ci_buf[obase + j] = s0 + li;
        ov_buf[obase + j] = ovv;
    }
}

// ---------------------------------------------------------------------------
// K2: threshold + positives + DIoU. One wave per (b,o). (Unchanged, passed.)
// ---------------------------------------------------------------------------
__global__ __launch_bounds__(256) void assign2_kernel(
    const float* __restrict__ locs,
    const float* __restrict__ boxes,
    const float* __restrict__ priors,
    const int* __restrict__ ci_buf,
    const float* __restrict__ ov_buf,
    int* __restrict__ winner,
    double* __restrict__ accum)
{
    const int w = threadIdx.x >> 6, lane = threadIdx.x & 63;
    const int bo = blockIdx.x * 4 + w;
    const int b = bo >> 4, o = bo & 15;

    const float4 bb = reinterpret_cast<const float4*>(boxes)[bo];
    const float bx0 = bb.x, by0 = bb.y, bx1 = bb.z, by1 = bb.w;
    const float bcx = (bx0 + bx1) * 0.5f, bcy = (by0 + by1) * 0.5f;
    const float barea = (bx1 - bx0) * (by1 - by0);

    int my_ci = 0; float ov = 0.f;
    if (lane < 49) {
        my_ci = ci_buf[bo * 64 + lane];
        ov    = ov_buf[bo * 64 + lane];
    }

    float sum = 0.f;
    for (int i = 0; i < 49; ++i) sum += __shfl(ov, i);
    const float mean = sum / 49.f;
    float ss = 0.f;
    for (int i = 0; i < 49; ++i) { float dd = __shfl(ov, i) - mean; ss += dd * dd; }
    const float thr = mean + sqrtf(ss / 48.f);

    float lloc = 0.f; int lcnt = 0;
    if (lane < 49) {
        const float4 pp = reinterpret_cast<const float4*>(priors)[my_ci];
        const bool inside = (bx0 <= pp.x) && (pp.x <= bx1) &&
                            (by0 <= pp.y) && (pp.y <= by1);
        if (inside && ov > thr) {
            atomicMax(&winner[b * NP + my_ci], o);
            const float4 g = reinterpret_cast<const float4*>(locs)[b * NP + my_ci];
            const float cx = g.x * pp.z * 0.1f + pp.x;
            const float cy = g.y * pp.w * 0.1f + pp.y;
            const float ww = __expf(g.z * 0.2f) * pp.z;
            const float hh = __expf(g.w * 0.2f) * pp.w;
            const float p0 = cx - ww * 0.5f, p1 = cy - hh * 0.5f;
            const float p2 = cx + ww * 0.5f, p3 = cy + hh * 0.5f;
            const float iw = fmaxf(fminf(p2, bx1) - fmaxf(p0, bx0), 0.f);
            const float ih = fmaxf(fminf(p3, by1) - fmaxf(p1, by0), 0.f);
            const float inter = iw * ih;
            const float ap = fmaxf(p2 - p0, 0.f) * fmaxf(p3 - p1, 0.f);
            const float iou = inter / (ap + barea - inter + 1e-7f);
            const float cpx = (p0 + p2) * 0.5f, cpy = (p1 + p3) * 0.5f;
            const float d2 = (cpx - bcx) * (cpx - bcx) + (cpy - bcy) * (cpy - bcy);
            const float ex0 = fminf(p0, bx0), ey0 = fminf(p1, by0);
            const float ex1 = fmaxf(p2, bx1), ey1 = fmaxf(p3, by1);
            const float dg = (ex1 - ex0) * (ex1 - ex0) + (ey1 - ey0) * (ey1 - ey0) + 1e-7f;
            lloc = 1.f - iou + d2 / dg;
            lcnt = 1;
        }
    }
    #pragma unroll
    for (int off = 32; off > 0; off >>= 1) {
        lloc += __shfl_xor(lloc, off);
        lcnt += __shfl_xor(lcnt, off);
    }
    if (lane == 0 && lcnt > 0) {
        atomicAdd(&accum[1], (double)lloc);
        atomicAdd(&accum[2], (double)lcnt);
    }
}

// ---------------------------------------------------------------------------
// K3: focal stream (4 independent loads in flight per iteration) + row fixup.
// No fences, no completion counters — plain atomics only.
// ---------------------------------------------------------------------------
#define K3_BLOCKS 2048
#define K3_STRIDE (K3_BLOCKS * 256u)     // 524,288
__global__ __launch_bounds__(256) void focal_kernel(
    const float* __restrict__ scores,
    const int* __restrict__ winner,
    const int* __restrict__ labels,
    double* __restrict__ accum)
{
    const unsigned tid = blockIdx.x * 256 + threadIdx.x;
    const unsigned total4 = (unsigned)(NB * NP * NCLS / 4);  // 7,076,160
    const float4* s4 = reinterpret_cast<const float4*>(scores);

    float f0 = 0.f, f1 = 0.f, f2 = 0.f, f3 = 0.f;
    unsigned i = tid;
    // main: 4 independent coalesced float4 loads in flight per iteration
    // total4 / K3_STRIDE = 13.5 chunks -> 3 full iterations, then remainder
    for (; i + 3u * K3_STRIDE < total4; i += 4u * K3_STRIDE) {
        const float4 va = s4[i];
        const float4 vb = s4[i + K3_STRIDE];
        const float4 vc = s4[i + 2u * K3_STRIDE];
        const float4 vd = s4[i + 3u * K3_STRIDE];
        f0 += focal_neg(va.x); f0 += focal_neg(va.y);
        f0 += focal_neg(va.z); f0 += focal_neg(va.w);
        f1 += focal_neg(vb.x); f1 += focal_neg(vb.y);
        f1 += focal_neg(vb.z); f1 += focal_neg(vb.w);
        f2 += focal_neg(vc.x); f2 += focal_neg(vc.y);
        f2 += focal_neg(vc.z); f2 += focal_neg(vc.w);
        f3 += focal_neg(vd.x); f3 += focal_neg(vd.y);
        f3 += focal_neg(vd.z); f3 += focal_neg(vd.w);
    }
    for (; i < total4; i += K3_STRIDE) {
        const float4 va = s4[i];
        f0 += focal_neg(va.x); f0 += focal_neg(va.y);
        f0 += focal_neg(va.z); f0 += focal_neg(va.w);
    }

    // per-row one-hot correction
    double dsum = (double)((f0 + f1) + (f2 + f3));
    if (tid < NROWS) {
        const int w = winner[tid];
        const int L = (w >= 0) ? labels[(tid / NP) * NO + w] : 0;
        const float s = scores[tid * NCLS + L];
        dsum += (double)focal_pos(s) - (double)focal_neg(s);
    }

    // block reduce + one atomic
    #pragma unroll
    for (int off = 32; off > 0; off >>= 1) dsum += __shfl_xor(dsum, off);
    __shared__ double redd[4];
    const int wid = threadIdx.x >> 6, lane = threadIdx.x & 63;
    if (lane == 0) redd[wid] = dsum;
    __syncthreads();
    if (threadIdx.x == 0)
        atomicAdd(&accum[0], redd[0] + redd[1] + redd[2] + redd[3]);
}

__global__ __launch_bounds__(64) void finalize_kernel(
    const double* __restrict__ accum, float* __restrict__ out)
{
    if (threadIdx.x == 0) {
        double conf = accum[0] / (double)NROWS;
        double cnt = accum[2];
        double loc = accum[1] / (cnt > 1.0 ? cnt : 1.0);
        out[0] = (float)(conf + loc);
    }
}

extern "C" void kernel_launch(void* const* d_in, const int* in_sizes, int n_in,
                              void* d_out, int out_size, void* d_ws, size_t ws_size,
                              hipStream_t stream) {
    const float* locs   = (const float*)d_in[0];
    const float* scores = (const float*)d_in[1];
    const float* boxes  = (const float*)d_in[2];
    const int*   labels = (const int*)d_in[3];
    const float* priors = (const float*)d_in[4];
    float* out = (float*)d_out;

    double* accum  = (double*)((char*)d_ws + WS_ACCUM);
    int*    winner = (int*)((char*)d_ws + WS_WINNER);
    int*    ci_buf = (int*)((char*)d_ws + WS_CI);
    float*  ov_buf = (float*)((char*)d_ws + WS_OV);

    topk_kernel<<<48, 256, 0, stream>>>(boxes, ci_buf, ov_buf, winner, accum);
    assign2_kernel<<<256, 256, 0, stream>>>(locs, boxes, priors, ci_buf, ov_buf,
                                            winner, accum);
    focal_kernel<<<K3_BLOCKS, 256, 0, stream>>>(scores, winner, labels, accum);
    finalize_kernel<<<1, 64, 0, stream>>>(accum, out);
}

// Round 11
// 200.696 us; speedup vs baseline: 1.4261x; 1.1641x over previous
//
#include <hip/hip_runtime.h>
#include <float.h>
#include <limits.h>

#define NB 64
#define NO 16
#define NP 5460
#define NCLS 81
#define NROWS (NB * NP)            // 349,440

// ws layout (bytes) — no global atomics anywhere; per-block/wave partials
#define WS_PCONF   256             // 2048 doubles  [256, 16640)
#define WS_PLOC    16640           // 1024 doubles  [16640, 24832)
#define WS_PCNT    24832           // 1024 doubles  [24832, 33024)
#define WS_WINNER  33024           // NROWS ints    [33024, 1430784)
#define WS_CI      1430784         // 1024*64 ints  [.., 1692928)
#define WS_OV      1692928         // 1024*64 floats

// ---------------------------------------------------------------------------
// Focal helpers — bitwise-identical between stream and fixup.
// rcpf = single v_rcp_f32 (1 ulp), not the __frcp_rn div sequence.
// ---------------------------------------------------------------------------
__device__ __forceinline__ float focal_neg(float s) {
    float e = __expf(-fabsf(s));            // exp(-|s|) in (0,1]
    float l1p = __logf(1.f + e);
    float q = __builtin_amdgcn_rcpf(1.f + e);
    float p = (s >= 0.f) ? q : e * q;       // sigmoid(s)
    return 0.75f * p * p * (fmaxf(s, 0.f) + l1p);
}
__device__ __forceinline__ float focal_pos(float s) {
    float e = __expf(-fabsf(s));
    float l1p = __logf(1.f + e);
    float q = __builtin_amdgcn_rcpf(1.f + e);
    float omp = (s >= 0.f) ? e * q : q;     // 1 - sigmoid(s)
    return 0.25f * omp * omp * (fmaxf(-s, 0.f) + l1p);
}

// ---------------------------------------------------------------------------
// K1: winner clear + analytic top-9 per (bo, level). (Logic unchanged, passed.)
// ---------------------------------------------------------------------------
__global__ __launch_bounds__(256) void topk_kernel(
    const float* __restrict__ boxes,   // [NB*NO, 4] xyxy
    int* __restrict__ ci_buf,          // [1024][64]
    float* __restrict__ ov_buf,        // [1024][64]
    int* __restrict__ winner)          // [NROWS]
{
    const int gtid = blockIdx.x * 256 + threadIdx.x;   // 0..12287

    // winner = -1 (349,440 ints = 87,360 int4)
    int4* w4 = reinterpret_cast<int4*>(winner);
    for (int i = gtid; i < NROWS / 4; i += 48 * 256)
        w4[i] = make_int4(-1, -1, -1, -1);

    if (gtid >= 6144) return;
    const int l  = gtid >> 10;
    const int bo = gtid & 1023;

    const int fms[6]   = {64, 32, 16, 8, 4, 2};
    const int lg2s[6]  = {6, 5, 4, 3, 2, 1};
    const int s0s[6]   = {0, 4096, 5120, 5376, 5440, 5456};
    const int basec[6] = {0, 9, 18, 27, 36, 45};
    const int fm = fms[l];
    const int lg2 = lg2s[l];
    const float fmf = (float)fm;

    const float4 bb = reinterpret_cast<const float4*>(boxes)[bo];
    const float bx0 = bb.x, by0 = bb.y, bx1 = bb.z, by1 = bb.w;
    const float bcx = (bx0 + bx1) * 0.5f;
    const float bcy = (by0 + by1) * 0.5f;
    const float barea = (bx1 - bx0) * (by1 - by0);

    int wx0 = 0, wy0 = 0, wnx = fm, wny = fm;
    if (fm >= 5) {
        int jx = (int)floorf(bcx * fmf);
        int jy = (int)floorf(bcy * fmf);
        jx = jx < 0 ? 0 : (jx > fm - 1 ? fm - 1 : jx);
        jy = jy < 0 ? 0 : (jy > fm - 1 ? fm - 1 : jy);
        wx0 = jx - 2; wx0 = wx0 < 0 ? 0 : (wx0 > fm - 5 ? fm - 5 : wx0);
        wy0 = jy - 2; wy0 = wy0 < 0 ? 0 : (wy0 > fm - 5 ? fm - 5 : wy0);
        wnx = 5; wny = 5;
    }

    float bv[9]; int bix[9];
    #pragma unroll
    for (int j = 0; j < 9; ++j) { bv[j] = FLT_MAX; bix[j] = INT_MAX; }

    for (int yy = 0; yy < wny; ++yy) {
        const int iy = wy0 + yy;
        const float py = ((float)iy + 0.5f) / fmf;
        const float dy = bcy - py;
        const float dy2 = dy * dy;
        for (int xx = 0; xx < wnx; ++xx) {
            const int ix = wx0 + xx;
            const float px = ((float)ix + 0.5f) / fmf;
            const float dx = bcx - px;
            const float d = dx * dx + dy2;
            const int gi = (iy << lg2) + ix;
            #pragma unroll
            for (int j = 8; j >= 0; --j) {
                bool ltp = (j > 0) ? (d < bv[j - 1]) : false;
                bool ltj = (d < bv[j]);
                float sv = ltp ? bv[j - 1] : (ltj ? d : bv[j]);
                int   si = ltp ? bix[j - 1] : (ltj ? gi : bix[j]);
                bv[j] = sv; bix[j] = si;
            }
        }
    }

    const int n = fm * fm;
    const int k = n < 9 ? n : 9;
    const float hw = 0.75f / fmf;
    const int obase = bo * 64 + basec[l];
    const int s0 = s0s[l];

    for (int j = 0; j < k; ++j) {
        const int li = bix[j];
        const int iy = li >> lg2, ix = li & (fm - 1);
        const float pcx = ((float)ix + 0.5f) / fmf;
        const float pcy = ((float)iy + 0.5f) / fmf;
        const float px0 = pcx - hw, py0 = pcy - hw;
        const float px1 = pcx + hw, py1 = pcy + hw;
        const float iw = fmaxf(fminf(bx1, px1) - fmaxf(bx0, px0), 0.f);
        const float ih = fmaxf(fminf(by1, py1) - fmaxf(by0, py0), 0.f);
        const float inter = iw * ih;
        const float parea = (px1 - px0) * (py1 - py0);
        const float ovv = inter / (barea + parea - inter + 1e-10f);
        ci_buf[obase + j] = s0 + li;
        ov_buf[obase + j] = ovv;
    }
}

// ---------------------------------------------------------------------------
// K2: threshold + positives + DIoU. One wave per (b,o); writes per-wave
// partials (NO atomics except winner's int atomicMax, which is sparse).
// ---------------------------------------------------------------------------
__global__ __launch_bounds__(256) void assign2_kernel(
    const float* __restrict__ locs,
    const float* __restrict__ boxes,
    const float* __restrict__ priors,
    const int* __restrict__ ci_buf,
    const float* __restrict__ ov_buf,
    int* __restrict__ winner,
    double* __restrict__ p_loc,        // [1024]
    double* __restrict__ p_cnt)        // [1024]
{
    const int w = threadIdx.x >> 6, lane = threadIdx.x & 63;
    const int bo = blockIdx.x * 4 + w;
    const int b = bo >> 4, o = bo & 15;

    const float4 bb = reinterpret_cast<const float4*>(boxes)[bo];
    const float bx0 = bb.x, by0 = bb.y, bx1 = bb.z, by1 = bb.w;
    const float bcx = (bx0 + bx1) * 0.5f, bcy = (by0 + by1) * 0.5f;
    const float barea = (bx1 - bx0) * (by1 - by0);

    int my_ci = 0; float ov = 0.f;
    if (lane < 49) {
        my_ci = ci_buf[bo * 64 + lane];
        ov    = ov_buf[bo * 64 + lane];
    }

    float sum = 0.f;
    for (int i = 0; i < 49; ++i) sum += __shfl(ov, i);
    const float mean = sum / 49.f;
    float ss = 0.f;
    for (int i = 0; i < 49; ++i) { float dd = __shfl(ov, i) - mean; ss += dd * dd; }
    const float thr = mean + sqrtf(ss / 48.f);

    float lloc = 0.f; int lcnt = 0;
    if (lane < 49) {
        const float4 pp = reinterpret_cast<const float4*>(priors)[my_ci];
        const bool inside = (bx0 <= pp.x) && (pp.x <= bx1) &&
                            (by0 <= pp.y) && (pp.y <= by1);
        if (inside && ov > thr) {
            atomicMax(&winner[b * NP + my_ci], o);
            const float4 g = reinterpret_cast<const float4*>(locs)[b * NP + my_ci];
            const float cx = g.x * pp.z * 0.1f + pp.x;
            const float cy = g.y * pp.w * 0.1f + pp.y;
            const float ww = __expf(g.z * 0.2f) * pp.z;
            const float hh = __expf(g.w * 0.2f) * pp.w;
            const float p0 = cx - ww * 0.5f, p1 = cy - hh * 0.5f;
            const float p2 = cx + ww * 0.5f, p3 = cy + hh * 0.5f;
            const float iw = fmaxf(fminf(p2, bx1) - fmaxf(p0, bx0), 0.f);
            const float ih = fmaxf(fminf(p3, by1) - fmaxf(p1, by0), 0.f);
            const float inter = iw * ih;
            const float ap = fmaxf(p2 - p0, 0.f) * fmaxf(p3 - p1, 0.f);
            const float iou = inter / (ap + barea - inter + 1e-7f);
            const float cpx = (p0 + p2) * 0.5f, cpy = (p1 + p3) * 0.5f;
            const float d2 = (cpx - bcx) * (cpx - bcx) + (cpy - bcy) * (cpy - bcy);
            const float ex0 = fminf(p0, bx0), ey0 = fminf(p1, by0);
            const float ex1 = fmaxf(p2, bx1), ey1 = fmaxf(p3, by1);
            const float dg = (ex1 - ex0) * (ex1 - ex0) + (ey1 - ey0) * (ey1 - ey0) + 1e-7f;
            lloc = 1.f - iou + d2 / dg;
            lcnt = 1;
        }
    }
    #pragma unroll
    for (int off = 32; off > 0; off >>= 1) {
        lloc += __shfl_xor(lloc, off);
        lcnt += __shfl_xor(lcnt, off);
    }
    if (lane == 0) {
        p_loc[bo] = (double)lloc;
        p_cnt[bo] = (double)lcnt;
    }
}

// ---------------------------------------------------------------------------
// K3: focal stream (4 independent loads in flight) + row fixup.
// Per-block partial write — NO global atomics.
// ---------------------------------------------------------------------------
#define K3_BLOCKS 2048
#define K3_STRIDE (K3_BLOCKS * 256u)     // 524,288
__global__ __launch_bounds__(256) void focal_kernel(
    const float* __restrict__ scores,
    const int* __restrict__ winner,
    const int* __restrict__ labels,
    double* __restrict__ p_conf)       // [K3_BLOCKS]
{
    const unsigned tid = blockIdx.x * 256 + threadIdx.x;
    const unsigned total4 = (unsigned)(NB * NP * NCLS / 4);  // 7,076,160
    const float4* s4 = reinterpret_cast<const float4*>(scores);

    float f0 = 0.f, f1 = 0.f, f2 = 0.f, f3 = 0.f;
    unsigned i = tid;
    for (; i + 3u * K3_STRIDE < total4; i += 4u * K3_STRIDE) {
        const float4 va = s4[i];
        const float4 vb = s4[i + K3_STRIDE];
        const float4 vc = s4[i + 2u * K3_STRIDE];
        const float4 vd = s4[i + 3u * K3_STRIDE];
        f0 += focal_neg(va.x); f0 += focal_neg(va.y);
        f0 += focal_neg(va.z); f0 += focal_neg(va.w);
        f1 += focal_neg(vb.x); f1 += focal_neg(vb.y);
        f1 += focal_neg(vb.z); f1 += focal_neg(vb.w);
        f2 += focal_neg(vc.x); f2 += focal_neg(vc.y);
        f2 += focal_neg(vc.z); f2 += focal_neg(vc.w);
        f3 += focal_neg(vd.x); f3 += focal_neg(vd.y);
        f3 += focal_neg(vd.z); f3 += focal_neg(vd.w);
    }
    for (; i < total4; i += K3_STRIDE) {
        const float4 va = s4[i];
        f0 += focal_neg(va.x); f0 += focal_neg(va.y);
        f0 += focal_neg(va.z); f0 += focal_neg(va.w);
    }

    double dsum = (double)((f0 + f1) + (f2 + f3));
    if (tid < NROWS) {
        const int w = winner[tid];
        const int L = (w >= 0) ? labels[(tid / NP) * NO + w] : 0;
        const float s = scores[tid * NCLS + L];
        dsum += (double)focal_pos(s) - (double)focal_neg(s);
    }

    #pragma unroll
    for (int off = 32; off > 0; off >>= 1) dsum += __shfl_xor(dsum, off);
    __shared__ double redd[4];
    const int wid = threadIdx.x >> 6, lane = threadIdx.x & 63;
    if (lane == 0) redd[wid] = dsum;
    __syncthreads();
    if (threadIdx.x == 0)
        p_conf[blockIdx.x] = redd[0] + redd[1] + redd[2] + redd[3];
}

// ---------------------------------------------------------------------------
// K4: sum all partials, finalize. One 256-thread block.
// ---------------------------------------------------------------------------
__global__ __launch_bounds__(256) void finalize_kernel(
    const double* __restrict__ p_conf,   // [2048]
    const double* __restrict__ p_loc,    // [1024]
    const double* __restrict__ p_cnt,    // [1024]
    float* __restrict__ out)
{
    double c = 0.0, l = 0.0, n = 0.0;
    for (int i = threadIdx.x; i < K3_BLOCKS; i += 256) c += p_conf[i];
    for (int i = threadIdx.x; i < 1024; i += 256) { l += p_loc[i]; n += p_cnt[i]; }
    #pragma unroll
    for (int off = 32; off > 0; off >>= 1) {
        c += __shfl_xor(c, off);
        l += __shfl_xor(l, off);
        n += __shfl_xor(n, off);
    }
    __shared__ double rc[4], rl[4], rn[4];
    const int wid = threadIdx.x >> 6, lane = threadIdx.x & 63;
    if (lane == 0) { rc[wid] = c; rl[wid] = l; rn[wid] = n; }
    __syncthreads();
    if (threadIdx.x == 0) {
        double conf = (rc[0] + rc[1] + rc[2] + rc[3]) / (double)NROWS;
        double loc  = rl[0] + rl[1] + rl[2] + rl[3];
        double cnt  = rn[0] + rn[1] + rn[2] + rn[3];
        out[0] = (float)(conf + loc / (cnt > 1.0 ? cnt : 1.0));
    }
}

extern "C" void kernel_launch(void* const* d_in, const int* in_sizes, int n_in,
                              void* d_out, int out_size, void* d_ws, size_t ws_size,
                              hipStream_t stream) {
    const float* locs   = (const float*)d_in[0];
    const float* scores = (const float*)d_in[1];
    const float* boxes  = (const float*)d_in[2];
    const int*   labels = (const int*)d_in[3];
    const float* priors = (const float*)d_in[4];
    float* out = (float*)d_out;

    double* p_conf = (double*)((char*)d_ws + WS_PCONF);
    double* p_loc  = (double*)((char*)d_ws + WS_PLOC);
    double* p_cnt  = (double*)((char*)d_ws + WS_PCNT);
    int*    winner = (int*)((char*)d_ws + WS_WINNER);
    int*    ci_buf = (int*)((char*)d_ws + WS_CI);
    float*  ov_buf = (float*)((char*)d_ws + WS_OV);

    topk_kernel<<<48, 256, 0, stream>>>(boxes, ci_buf, ov_buf, winner);
    assign2_kernel<<<256, 256, 0, stream>>>(locs, boxes, priors, ci_buf, ov_buf,
                                            winner, p_loc, p_cnt);
    focal_kernel<<<K3_BLOCKS, 256, 0, stream>>>(scores, winner, labels, p_conf);
    finalize_kernel<<<1, 256, 0, stream>>>(p_conf, p_loc, p_cnt, out);
}